// Round 8
// baseline (777.439 us; speedup 1.0000x reference)
//
#include <hip/hip_runtime.h>
#include <hip/hip_bf16.h>

typedef __bf16 bf16x8 __attribute__((ext_vector_type(8)));
typedef float f32x4 __attribute__((ext_vector_type(4)));
typedef unsigned long long ull;

// d_out layout (f32): hs[128][64][1024] | h_n[64][1024] | c_n[64][1024]
#define HN_OFF 8388608u
#define CN_OFF 8454144u

__device__ __forceinline__ float bf2f(ushort u) {
  union { unsigned int i; float f; } x; x.i = ((unsigned int)u) << 16; return x.f;
}
__device__ __forceinline__ ushort f2bf(float f) {
  union { float f; unsigned int i; } x; x.f = f;
  unsigned int r = x.i + 0x7FFFu + ((x.i >> 16) & 1u);
  return (ushort)(r >> 16);
}

// ---------------- f32 -> bf16 converters ----------------
__global__ __launch_bounds__(256) void conv_copy(const float* __restrict__ s,
                                                 ushort* __restrict__ d, int n4) {
  int i = blockIdx.x * 256 + threadIdx.x;
  if (i < n4) {
    float4 v = reinterpret_cast<const float4*>(s)[i];
    ushort4 o; o.x = f2bf(v.x); o.y = f2bf(v.y); o.z = f2bf(v.z); o.w = f2bf(v.w);
    reinterpret_cast<ushort4*>(d)[i] = o;
  }
}

// h0 (64x1024 f32) -> blocked bf16 layout [bg(4)][kk(32)][lane(64)][8]
__global__ __launch_bounds__(256) void conv_h0(const float* __restrict__ h0,
                                               ushort* __restrict__ hb) {
  int t = blockIdx.x * 256 + threadIdx.x;  // 8192 threads: b = t>>7, chunk c = t&127
  int b = t >> 7, c = t & 127;             // j = c*8
  float4 v0 = *reinterpret_cast<const float4*>(h0 + (size_t)b * 1024 + c * 8);
  float4 v1 = *reinterpret_cast<const float4*>(h0 + (size_t)b * 1024 + c * 8 + 4);
  size_t de = ((size_t)(b >> 4) * 32 + (c >> 2)) * 512 + (size_t)(c & 3) * 128 + (b & 15) * 8;
  ushort* d = hb + de;
  d[0] = f2bf(v0.x); d[1] = f2bf(v0.y); d[2] = f2bf(v0.z); d[3] = f2bf(v0.w);
  d[4] = f2bf(v1.x); d[5] = f2bf(v1.y); d[6] = f2bf(v1.z); d[7] = f2bf(v1.w);
}

// Extract W_a = W_ih[:, 512:1024] -> bf16 [4096][512]
__global__ __launch_bounds__(256) void conv_wa(const float* __restrict__ Wih,
                                               ushort* __restrict__ Wa) {
  int t = blockIdx.x * 256 + threadIdx.x;  // 4096*128 threads
  int g = t >> 7, c = t & 127;
  float4 v = *reinterpret_cast<const float4*>(Wih + (size_t)g * 1024 + 512 + c * 4);
  ushort4 o; o.x = f2bf(v.x); o.y = f2bf(v.y); o.z = f2bf(v.z); o.w = f2bf(v.w);
  *reinterpret_cast<ushort4*>(Wa + (size_t)g * 512 + c * 4) = o;
}

// ---------------- base[g][b] = input[b]·W_x[g] + b_ih[g] + b_hh[g] ----------------
__global__ __launch_bounds__(256) void base_kernel(const float* __restrict__ x,
    const float* __restrict__ Wih, const float* __restrict__ bih,
    const float* __restrict__ bhh, float* __restrict__ baseT) {
  int t = blockIdx.x * 256 + threadIdx.x;  // 4096*64 threads
  int g = t >> 6, b = t & 63;
  const float4* xv = reinterpret_cast<const float4*>(x + (size_t)b * 512);
  const float4* wv = reinterpret_cast<const float4*>(Wih + (size_t)g * 1024);
  float s = 0.f;
  #pragma unroll 4
  for (int a = 0; a < 128; ++a) {
    float4 xa = xv[a], wa = wv[a];
    s += xa.x * wa.x + xa.y * wa.y + xa.z * wa.z + xa.w * wa.w;
  }
  baseT[t] = s + bih[g] + bhh[g];
}

// ---------------- pre[g][lb] = sum_a Wa[g][a]*acts[lb][a] + base[g][lb%64] ----------------
__global__ __launch_bounds__(256, 1) void gemm_pre(
    const ushort* __restrict__ A,    // Wa bf16 [4096][512]
    const ushort* __restrict__ B,    // acts bf16 [8192][512]
    const float* __restrict__ baseT, // [4096][64]
    ushort* __restrict__ C) {        // pre bf16 [4096][8192]
  __shared__ ushort At[128 * 64];
  __shared__ ushort Bt[128 * 64];
  const int tid = threadIdx.x;
  const int m0 = blockIdx.x * 128;
  const int n0 = blockIdx.y * 128;
  const int wave = tid >> 6, lane = tid & 63;
  const int wm = wave >> 1, wn = wave & 1;
  const int q = lane >> 4, lc = lane & 15;

  f32x4 acc[4][4];
  #pragma unroll
  for (int mt = 0; mt < 4; ++mt)
    #pragma unroll
    for (int nt = 0; nt < 4; ++nt)
      acc[mt][nt] = (f32x4){0.f, 0.f, 0.f, 0.f};

  for (int k0 = 0; k0 < 512; k0 += 64) {
    __syncthreads();
    for (int idx = tid; idx < 1024; idx += 256) {
      int r = idx >> 3, ch = idx & 7;
      *reinterpret_cast<uint4*>(&At[r * 64 + (ch ^ (r & 7)) * 8]) =
          *reinterpret_cast<const uint4*>(A + (size_t)(m0 + r) * 512 + k0 + ch * 8);
      *reinterpret_cast<uint4*>(&Bt[r * 64 + (ch ^ (r & 7)) * 8]) =
          *reinterpret_cast<const uint4*>(B + (size_t)(n0 + r) * 512 + k0 + ch * 8);
    }
    __syncthreads();
    #pragma unroll
    for (int kk = 0; kk < 2; ++kk) {
      bf16x8 af[4], bfr[4];
      #pragma unroll
      for (int mt = 0; mt < 4; ++mt) {
        int r = wm * 64 + mt * 16 + lc;
        af[mt] = *reinterpret_cast<const bf16x8*>(&At[r * 64 + ((kk * 4 + q) ^ (r & 7)) * 8]);
      }
      #pragma unroll
      for (int nt = 0; nt < 4; ++nt) {
        int r = wn * 64 + nt * 16 + lc;
        bfr[nt] = *reinterpret_cast<const bf16x8*>(&Bt[r * 64 + ((kk * 4 + q) ^ (r & 7)) * 8]);
      }
      #pragma unroll
      for (int mt = 0; mt < 4; ++mt)
        #pragma unroll
        for (int nt = 0; nt < 4; ++nt)
          acc[mt][nt] = __builtin_amdgcn_mfma_f32_16x16x32_bf16(af[mt], bfr[nt], acc[mt][nt], 0, 0, 0);
    }
  }
  #pragma unroll
  for (int mt = 0; mt < 4; ++mt) {
    #pragma unroll
    for (int nt = 0; nt < 4; ++nt) {
      int g = m0 + wm * 64 + mt * 16 + q * 4;
      int lb = n0 + wn * 64 + nt * 16 + lc;
      int b = lb & 63;
      #pragma unroll
      for (int i = 0; i < 4; ++i) {
        float v = acc[mt][nt][i] + baseT[(size_t)(g + i) * 64 + b];
        C[(size_t)(g + i) * 8192 + lb] = f2bf(v);
      }
    }
  }
}

// ---------------- persistent LSTM recurrence: W in regs, h shared via LDS ---
// 256 blocks x 256 threads (4 waves). Block (ug = bid>>2, bq = bid&3) computes
// units ug*16..+16 for batch quarter bq. W fragments resident in 128 VGPRs.
// Per step: wave w gates on ITS 16 producers, loads ITS 8 h-chunks (8 KB,
// sc0 sc1 MALL bypass), shares via 32 KB LDS; all waves ds_read A-frags.
// ALL inline-asm loads (pre prefetch + h chunks) are issued at ONE program
// point per iteration and drained by WAITG(0) before any compiler-visible
// use — divergent asm-load assignment was R7's correctness bug.
#define WAITG(n) asm volatile("s_waitcnt vmcnt(" #n ")" ::: "memory"); \
                 __builtin_amdgcn_sched_barrier(0);

__global__ __launch_bounds__(256, 1) void lstm_rec(
    const ushort* __restrict__ Whh,  // bf16 [4096][1024]
    const ushort* __restrict__ pre,  // bf16 [4096][8192]
    const float* __restrict__ c0,    // f32 [64][1024]
    const ushort* __restrict__ hbuf, // blocked bf16 [2][4][32][64][8] (read)
    ushort* __restrict__ hbw,        // same buffer, write alias
    float* __restrict__ out,
    int* __restrict__ flags) {       // [4 planes][64] ints at 16B stride
  __shared__ ushort hl[32 * 512];    // 32 KB: [kk(32)][lane(64)][8]
  __shared__ ushort hstage[16 * 16]; // [batch-local 16][unit-local 16]
  const int tid = threadIdx.x;
  const int bid = blockIdx.x;
  const int bq = bid & 3;            // batch-quarter plane
  const int ug = bid >> 2;           // unit group (0..63)
  const int w = tid >> 6;            // wave
  const int lane = tid & 63;
  const int q = lane >> 4;
  const int lc = lane & 15;
  const int ul = w * 4 + (lc & 3);             // unit-local (0..15)
  const int u = ug * 16 + ul;                  // hidden unit for this column
  const int gr = u + ((lc >> 2) << 10);        // gate row (gate = lc>>2)
  const int bbase = bq * 16 + q * 4;           // global batch base for acc rows
  const bool cellLane = ((lc & 12) == 0);      // lc in 0..3 -> owns unit u

  // ---- W_hh fragments resident in registers (one acc tile: 16b x 16g) ----
  bf16x8 wfr[32];
  {
    const ushort* wr = Whh + (size_t)gr * 1024 + q * 8;
    #pragma unroll
    for (int kk = 0; kk < 32; ++kk)
      wfr[kk] = *reinterpret_cast<const bf16x8*>(wr + kk * 32);
  }

  float cst[4];
  #pragma unroll
  for (int i = 0; i < 4; ++i)
    cst[i] = cellLane ? c0[(size_t)(bbase + i) * 1024 + u] : 0.f;

  const unsigned va_base = ((unsigned)gr * 8192u + (unsigned)bbase) * 2u;
  // h-load voffset: plane base | chunk (w*8+k) | lane; + parity<<17 per step
  const unsigned hob0 = ((unsigned)bq << 15) | ((unsigned)(w * 8) << 10) |
                        ((unsigned)lane << 4);
  // this wave's producer flag (one of 16, lane-cyclic)
  const int myflag = (bq * 64 + w * 16 + (lane & 15)) * 4;

  // pre slice for t=0
  ushort4 pa = *reinterpret_cast<const ushort4*>(pre + (size_t)gr * 8192 + bbase);

  for (int t = 0; t < 128; ++t) {
    // gate: wave w waits only for the 16 producers feeding its 8 chunks
    if (t > 0) {
      for (;;) {
        int f = __hip_atomic_load(&flags[myflag], __ATOMIC_RELAXED,
                                  __HIP_MEMORY_SCOPE_AGENT);
        if (__all(f >= t)) break;
      }
    }

    // pre prefetch for t+1 — SAME program point for all waves (no divergent
    // asm-load assignment), drained by WAITG(0) below before any use.
    const int tn = (t < 127) ? t + 1 : t;
    ushort4 npa;
    {
      unsigned va = va_base + (unsigned)tn * 128u;
      asm volatile("global_load_dwordx2 %0, %1, %2" : "=v"(npa) : "v"(va), "s"(pre));
    }

    // issue this wave's 8 h-chunk loads (sc0 sc1: bypass L1/L2, read at MALL)
    const unsigned hob = hob0 | ((unsigned)(t & 1) << 17);
    bf16x8 haf[8];
    #pragma unroll
    for (int k = 0; k < 8; ++k) {
      unsigned voff = hob + ((unsigned)k << 10);
      asm volatile("global_load_dwordx4 %0, %1, %2 sc0 sc1"
                   : "=v"(haf[k]) : "v"(voff), "s"(hbuf));
    }
    WAITG(0)
    #pragma unroll
    for (int k = 0; k < 8; ++k)
      *reinterpret_cast<bf16x8*>(&hl[(w * 8 + k) * 512 + lane * 8]) = haf[k];
    __syncthreads();  // hl complete (also: prev iteration fully done)

    f32x4 acc_a, acc_b;
    acc_a[0] = bf2f(pa.x); acc_a[1] = bf2f(pa.y); acc_a[2] = bf2f(pa.z); acc_a[3] = bf2f(pa.w);
    acc_b = (f32x4){0.f, 0.f, 0.f, 0.f};

    // 32 MFMAs as two 16-chains; A-frags from LDS (linear ds_read_b128)
    #pragma unroll
    for (int kk = 0; kk < 16; ++kk) {
      bf16x8 af = *reinterpret_cast<const bf16x8*>(&hl[kk * 512 + lane * 8]);
      acc_a = __builtin_amdgcn_mfma_f32_16x16x32_bf16(af, wfr[kk], acc_a, 0, 0, 0);
    }
    #pragma unroll
    for (int kk = 16; kk < 32; ++kk) {
      bf16x8 af = *reinterpret_cast<const bf16x8*>(&hl[kk * 512 + lane * 8]);
      acc_b = __builtin_amdgcn_mfma_f32_16x16x32_bf16(af, wfr[kk], acc_b, 0, 0, 0);
    }
    f32x4 acc;
    #pragma unroll
    for (int i = 0; i < 4; ++i) acc[i] = acc_a[i] + acc_b[i];

    // join i/f/g/o across lanes (unit u at lanes lc, lc^4, lc^8, lc^12)
    float fv[4], gv[4], ov[4];
    #pragma unroll
    for (int i = 0; i < 4; ++i) {
      fv[i] = __shfl_xor(acc[i], 4, 64);
      gv[i] = __shfl_xor(acc[i], 8, 64);
      ov[i] = __shfl_xor(acc[i], 12, 64);
    }
    float hv[4];
    if (cellLane) {
      #pragma unroll
      for (int i = 0; i < 4; ++i) {
        float ig = 1.f / (1.f + __expf(-acc[i]));
        float fg = 1.f / (1.f + __expf(-fv[i]));
        float gg = tanhf(gv[i]);
        float og = 1.f / (1.f + __expf(-ov[i]));
        float cn = fg * cst[i] + ig * gg;
        hv[i] = og * tanhf(cn);
        cst[i] = cn;
        hstage[(q * 4 + i) * 16 + ul] = f2bf(hv[i]);
      }
    }

    if (t == 127) {
      if (cellLane) {
        #pragma unroll
        for (int i = 0; i < 4; ++i) {
          int b = bbase + i;
          out[((size_t)t * 64 + b) * 1024 + u] = hv[i];
          out[HN_OFF + (size_t)b * 1024 + u] = hv[i];
          out[CN_OFF + (size_t)b * 1024 + u] = cst[i];
        }
      }
      break;
    }

    __syncthreads();  // hstage ready

    // export h(t+1): wave 0 only (32 threads x 16B), then drain + publish.
    // vmcnt is 0 at this point for wave 0 (WAITG(0) drained all loads), so
    // the drain below waits ONLY on the export stores.
    if (tid < 32) {
      int bl = tid >> 1, ci = tid & 1;
      const ull* src = reinterpret_cast<const ull*>(&hstage[bl * 16 + ci * 8]);
      size_t de = ((size_t)((t + 1) & 1) << 16) + ((size_t)bq << 14) +
                  ((size_t)(ug >> 1) << 9) +
                  (size_t)(((ug * 2 + ci) & 3) * 16 + bl) * 8;
      ull* dst = reinterpret_cast<ull*>(hbw + de);
      __hip_atomic_store(dst, src[0], __ATOMIC_RELAXED, __HIP_MEMORY_SCOPE_AGENT);
      __hip_atomic_store(dst + 1, src[1], __ATOMIC_RELAXED, __HIP_MEMORY_SCOPE_AGENT);
    }
    if (w == 0) {
      asm volatile("s_waitcnt vmcnt(0)" ::: "memory");
      if (tid == 0)
        __hip_atomic_store(&flags[(bq * 64 + ug) * 4], t + 1, __ATOMIC_RELAXED,
                           __HIP_MEMORY_SCOPE_AGENT);
    }

    // hs out-writes overlap other blocks' consumption
    if (cellLane) {
      #pragma unroll
      for (int i = 0; i < 4; ++i)
        out[((size_t)t * 64 + bbase + i) * 1024 + u] = hv[i];
    }

    pa = npa;
  }
}

extern "C" void kernel_launch(void* const* d_in, const int* in_sizes, int n_in,
                              void* d_out, int out_size, void* d_ws, size_t ws_size,
                              hipStream_t stream) {
  const float* input = (const float*)d_in[0];  // (64,512)
  const float* acts  = (const float*)d_in[1];  // (128,64,512)
  const float* h0    = (const float*)d_in[2];  // (64,1024)
  const float* c0    = (const float*)d_in[3];  // (64,1024)
  const float* Wih   = (const float*)d_in[4];  // (4096,1024)
  const float* Whh   = (const float*)d_in[5];  // (4096,1024)
  const float* bih   = (const float*)d_in[6];  // (4096)
  const float* bhh   = (const float*)d_in[7];  // (4096)
  float* out = (float*)d_out;

  char* ws = (char*)d_ws;
  ushort* pre   = (ushort*)(ws);                 // 67,108,864 B
  ushort* actsb = (ushort*)(ws + 67108864);      //  8,388,608 B
  ushort* Wab   = (ushort*)(ws + 75497472);      //  4,194,304 B
  ushort* Whhb  = (ushort*)(ws + 79691776);      //  8,388,608 B
  float*  baseT = (float*) (ws + 88080384);      //  1,048,576 B
  ushort* hbuf  = (ushort*)(ws + 89128960);      //    262,144 B
  int*    flags = (int*)   (ws + 89391104);      //      8,192 B

  hipMemsetAsync(flags, 0, 8192, stream);
  conv_copy<<<4096, 256, 0, stream>>>(acts, actsb, 1048576);
  conv_copy<<<4096, 256, 0, stream>>>(Whh, Whhb, 1048576);
  conv_h0<<<32, 256, 0, stream>>>(h0, hbuf);
  conv_wa<<<2048, 256, 0, stream>>>(Wih, Wab);
  base_kernel<<<1024, 256, 0, stream>>>(input, Wih, bih, bhh, baseT);
  gemm_pre<<<dim3(32, 64), 256, 0, stream>>>(Wab, actsb, baseT, pre);
  lstm_rec<<<256, 256, 0, stream>>>(Whhb, pre, c0, hbuf, hbuf, out, flags);
}